// Round 1
// baseline (16205.141 us; speedup 1.0000x reference)
//
#include <hip/hip_runtime.h>
#include <hip/hip_bf16.h>
#include <cstdint>
#include <cstddef>

// ---------------- problem constants ----------------
#define BATCH    4
#define SEQ      1024
#define DMODEL   1152
#define NHEADS   16
#define HEADDIM  72
#define FFDIM    4304
#define NLAYERS  6
#define PATCHIN  588
#define LN_EPS   1e-6f

typedef float f32x4 __attribute__((ext_vector_type(4)));
typedef __bf16 bf16x8 __attribute__((ext_vector_type(8)));
typedef short s16x8 __attribute__((ext_vector_type(8)));
typedef short s16x4 __attribute__((ext_vector_type(4)));

__device__ __forceinline__ short f2bf(float f) {
  // fp32 -> bf16 bits, round-to-nearest-even
  unsigned u = __builtin_bit_cast(unsigned, f);
  u = (u + 0x7fffu + ((u >> 16) & 1u)) >> 16;
  return (short)u;
}

__device__ __forceinline__ float gelu_tanh(float x) {
  const float c0 = 0.7978845608028654f, c1 = 0.044715f;
  return 0.5f * x * (1.0f + tanhf(c0 * (x + c1 * x * x * x)));
}

// ---------------- bf16 MFMA GEMM ----------------
// C[M,N] = epilogue(A[M,K] @ B[K,N] + bias), A/B fp32 row-major, converted to
// bf16 at LDS staging. mode: 0 = +bias, 1 = +bias+R (residual), 2 = gelu(+bias)
#define BM 128
#define BN 128
#define BK 32
#define LDP 40   // LDS row stride in shorts (pad 32->40; 80B row keeps 16B align)

__global__ __launch_bounds__(256) void gemm_bf16(
    const float* __restrict__ A, const float* __restrict__ Bm,
    const float* __restrict__ bias, const float* __restrict__ Rres,
    float* __restrict__ C, int M, int N, int K, int mode)
{
  __shared__ __align__(16) short As[BM * LDP];
  __shared__ __align__(16) short Bs[BN * LDP];
  const int tid = threadIdx.x;
  const int wave = tid >> 6, lane = tid & 63;
  const int lr = lane & 15, lq = lane >> 4;
  const int m0 = blockIdx.y * BM, n0 = blockIdx.x * BN;
  const int wm = (wave & 1) * 64, wn = (wave >> 1) * 64;

  f32x4 acc[4][4];
#pragma unroll
  for (int i = 0; i < 4; ++i)
#pragma unroll
    for (int j = 0; j < 4; ++j) acc[i][j] = (f32x4)(0.0f);

  const int nk = (K + BK - 1) / BK;
  for (int kt = 0; kt < nk; ++kt) {
    const int k0 = kt * BK;
    // --- stage A tile: 128 rows x 32 k (1024 float4 slots / 256 threads) ---
#pragma unroll
    for (int i = 0; i < 4; ++i) {
      int slot = tid + 256 * i;
      int row = slot >> 3, f4c = slot & 7;
      int gm = m0 + row, gk = k0 + f4c * 4;
      float4 v = make_float4(0.f, 0.f, 0.f, 0.f);
      if (gm < M) {
        const float* ar = A + (size_t)gm * K;
        if (gk + 3 < K) v = *(const float4*)(ar + gk);
        else {
          if (gk + 0 < K) v.x = ar[gk + 0];
          if (gk + 1 < K) v.y = ar[gk + 1];
          if (gk + 2 < K) v.z = ar[gk + 2];
          if (gk + 3 < K) v.w = ar[gk + 3];
        }
      }
      s16x4 sv = {f2bf(v.x), f2bf(v.y), f2bf(v.z), f2bf(v.w)};
      *(s16x4*)&As[row * LDP + f4c * 4] = sv;
    }
    // --- stage B tile transposed: Bs[n][k]; loads coalesced along n ---
#pragma unroll
    for (int i = 0; i < 4; ++i) {
      int slot = tid + 256 * i;
      int n = slot & 127, kq = slot >> 7;
      int gn = n0 + n;
      float v0 = 0.f, v1 = 0.f, v2 = 0.f, v3 = 0.f;
      if (gn < N) {
        int gk = k0 + kq * 4;
        const float* br = Bm + gn;
        if (gk + 0 < K) v0 = br[(size_t)(gk + 0) * N];
        if (gk + 1 < K) v1 = br[(size_t)(gk + 1) * N];
        if (gk + 2 < K) v2 = br[(size_t)(gk + 2) * N];
        if (gk + 3 < K) v3 = br[(size_t)(gk + 3) * N];
      }
      s16x4 sv = {f2bf(v0), f2bf(v1), f2bf(v2), f2bf(v3)};
      *(s16x4*)&Bs[n * LDP + kq * 4] = sv;
    }
    __syncthreads();
    // --- fragments + MFMA ---
    // a_frag[j] = A[m = lane&15][k = (lane>>4)*8 + j]; b_frag symmetric in n.
    s16x8 af[4], bfr[4];
#pragma unroll
    for (int mi = 0; mi < 4; ++mi)
      af[mi] = *(const s16x8*)&As[(wm + mi * 16 + lr) * LDP + lq * 8];
#pragma unroll
    for (int ni = 0; ni < 4; ++ni)
      bfr[ni] = *(const s16x8*)&Bs[(wn + ni * 16 + lr) * LDP + lq * 8];
#pragma unroll
    for (int mi = 0; mi < 4; ++mi)
#pragma unroll
      for (int ni = 0; ni < 4; ++ni)
        acc[mi][ni] = __builtin_amdgcn_mfma_f32_16x16x32_bf16(
            __builtin_bit_cast(bf16x8, af[mi]),
            __builtin_bit_cast(bf16x8, bfr[ni]), acc[mi][ni], 0, 0, 0);
    __syncthreads();
  }
  // --- epilogue: D[row=(lane>>4)*4+r][col=lane&15] (m89-verified layout) ---
#pragma unroll
  for (int ni = 0; ni < 4; ++ni) {
    int col = n0 + wn + ni * 16 + lr;
    if (col >= N) continue;
    float bv = bias[col];
#pragma unroll
    for (int mi = 0; mi < 4; ++mi) {
#pragma unroll
      for (int r = 0; r < 4; ++r) {
        int row = m0 + wm + mi * 16 + lq * 4 + r;
        if (row >= M) continue;
        float v = acc[mi][ni][r] + bv;
        if (mode == 1) v += Rres[(size_t)row * N + col];
        else if (mode == 2) v = gelu_tanh(v);
        C[(size_t)row * N + col] = v;
      }
    }
  }
}

// ---------------- LayerNorm (rows of 1152) ----------------
__global__ __launch_bounds__(256) void ln_kernel(
    const float* __restrict__ in, const float* __restrict__ w,
    const float* __restrict__ b, float* __restrict__ out)
{
  const int row = blockIdx.x, tid = threadIdx.x;
  __shared__ float buf[DMODEL];
  __shared__ float red[8];
  const float* x = in + (size_t)row * DMODEL;
  float s = 0.f;
  for (int i = tid; i < DMODEL; i += 256) { float v = x[i]; buf[i] = v; s += v; }
  for (int off = 32; off; off >>= 1) s += __shfl_down(s, off);
  if ((tid & 63) == 0) red[tid >> 6] = s;
  __syncthreads();
  const float mean = (red[0] + red[1] + red[2] + red[3]) * (1.0f / DMODEL);
  float vs = 0.f;
  for (int i = tid; i < DMODEL; i += 256) { float d = buf[i] - mean; vs += d * d; }
  for (int off = 32; off; off >>= 1) vs += __shfl_down(vs, off);
  if ((tid & 63) == 0) red[4 + (tid >> 6)] = vs;
  __syncthreads();
  const float var = (red[4] + red[5] + red[6] + red[7]) * (1.0f / DMODEL);
  const float rstd = rsqrtf(var + LN_EPS);
  float* o = out + (size_t)row * DMODEL;
  for (int i = tid; i < DMODEL; i += 256)
    o[i] = (buf[i] - mean) * rstd * w[i] + b[i];
}

// ---------------- position-embedding bilinear resize + add ----------------
__global__ __launch_bounds__(288) void pos_add_kernel(
    const float* __restrict__ pos, const int* __restrict__ ssp,
    float* __restrict__ hbuf)
{
  const int bs = blockIdx.x;
  const int b = bs >> 10, s = bs & (SEQ - 1);
  int hs, wd;
  // robust to int32 vs int64 spatial_shapes (int64 LE reads as [v,0,v,0,...])
  if (ssp[1] == 0 && ssp[3] == 0) { hs = ssp[b * 4]; wd = ssp[b * 4 + 2]; }
  else { hs = ssp[b * 2]; wd = ssp[b * 2 + 1]; }
  int r = 0, c = 0;
  if (s < hs * wd) { r = s / wd; c = s % wd; }
  const float fy = (r + 0.5f) * (16.0f / hs) - 0.5f;
  const float fx = (c + 0.5f) * (16.0f / wd) - 0.5f;
  const float y0f = floorf(fy), x0f = floorf(fx);
  const float ty = fy - y0f, tx = fx - x0f;
  const int y0 = (int)y0f, x0 = (int)x0f;
  const int y0c = min(max(y0, 0), 15), y1c = min(max(y0 + 1, 0), 15);
  const int x0c = min(max(x0, 0), 15), x1c = min(max(x0 + 1, 0), 15);
  const float w00 = (1.f - ty) * (1.f - tx), w01 = (1.f - ty) * tx;
  const float w10 = ty * (1.f - tx), w11 = ty * tx;
  const float* p00 = pos + (size_t)(y0c * 16 + x0c) * DMODEL;
  const float* p01 = pos + (size_t)(y0c * 16 + x1c) * DMODEL;
  const float* p10 = pos + (size_t)(y1c * 16 + x0c) * DMODEL;
  const float* p11 = pos + (size_t)(y1c * 16 + x1c) * DMODEL;
  float* hrow = hbuf + (size_t)bs * DMODEL;
  const int d0 = threadIdx.x * 4;
#pragma unroll
  for (int i = 0; i < 4; ++i) {
    int d = d0 + i;
    hrow[d] += w00 * p00[d] + w01 * p01[d] + w10 * p10[d] + w11 * p11[d];
  }
}

// ---------------- flash attention (fp32, online softmax) ----------------
// grid (SEQ/64, NHEADS, BATCH); q/k/v layout (b, s, h*72+d)
__global__ __launch_bounds__(256) void attn_kernel(
    const float* __restrict__ Q, const float* __restrict__ Kb,
    const float* __restrict__ Vb, const float* __restrict__ mask,
    float* __restrict__ O)
{
  __shared__ __align__(16) float Qt[64][72];   // 288B rows, 16B-aligned
  __shared__ __align__(16) float Kt[64][76];   // 304B rows -> conflict-free b128
  __shared__ __align__(16) float Vt[64][76];
  __shared__ float Ps[64][65];                 // odd stride: conflict-free
  __shared__ float madd[64];
  const int tid = threadIdx.x;
  const int q0 = blockIdx.x * 64, h = blockIdx.y, b = blockIdx.z;
  const float scale = 0.11785113019775793f;    // 1/sqrt(72)

  for (int idx = tid; idx < 64 * 72; idx += 256) {
    int qi = idx / 72, d = idx % 72;
    Qt[qi][d] = Q[((size_t)(b * SEQ + q0 + qi)) * DMODEL + h * HEADDIM + d];
  }
  const int ds = tid & 7, d0 = ds * 9;
  const int qp = tid >> 3, q1 = qp * 2, q2 = qp * 2 + 1;
  const int jj = tid & 63, qoff = tid >> 6;
  float m1 = -1e30f, l1 = 0.f, m2 = -1e30f, l2 = 0.f;
  float O1[9], O2[9];
#pragma unroll
  for (int i = 0; i < 9; ++i) { O1[i] = 0.f; O2[i] = 0.f; }

  for (int kt = 0; kt < SEQ / 64; ++kt) {
    const int k0 = kt * 64;
    __syncthreads();   // protect Kt/Vt/Ps from previous tile's consumers
    for (int idx = tid; idx < 64 * 72; idx += 256) {
      int j = idx / 72, d = idx % 72;
      size_t base = ((size_t)(b * SEQ + k0 + j)) * DMODEL + h * HEADDIM + d;
      Kt[j][d] = Kb[base];
      Vt[j][d] = Vb[base];
    }
    if (tid < 64)
      madd[tid] = (1.0f - mask[b * SEQ + k0 + tid]) * -3.4028234663852886e38f;
    __syncthreads();
    // scores: thread owns key jj, accumulates 16 queries (K-row reg-cached)
    {
      float accs[16];
#pragma unroll
      for (int ii = 0; ii < 16; ++ii) accs[ii] = 0.f;
      const float4* krow = (const float4*)&Kt[jj][0];
      for (int dq = 0; dq < 18; ++dq) {
        float4 kv = krow[dq];
#pragma unroll
        for (int ii = 0; ii < 16; ++ii) {
          const float4 qv = ((const float4*)&Qt[qoff + ii * 4][0])[dq];
          accs[ii] += kv.x * qv.x + kv.y * qv.y + kv.z * qv.z + kv.w * qv.w;
        }
      }
      float ma = madd[jj];
#pragma unroll
      for (int ii = 0; ii < 16; ++ii)
        Ps[qoff + ii * 4][jj] = accs[ii] * scale + ma;
    }
    __syncthreads();
    // online softmax + PV: thread owns 2 queries x 9 dims
    float tm1 = -1e30f, tm2 = -1e30f;
    for (int j = 0; j < 64; ++j) {
      tm1 = fmaxf(tm1, Ps[q1][j]);
      tm2 = fmaxf(tm2, Ps[q2][j]);
    }
    float nm1 = fmaxf(m1, tm1), nm2 = fmaxf(m2, tm2);
    float a1 = __expf(m1 - nm1), a2 = __expf(m2 - nm2);
#pragma unroll
    for (int i = 0; i < 9; ++i) { O1[i] *= a1; O2[i] *= a2; }
    l1 *= a1; l2 *= a2;
    for (int j = 0; j < 64; ++j) {
      float p1 = __expf(Ps[q1][j] - nm1);
      float p2 = __expf(Ps[q2][j] - nm2);
      l1 += p1; l2 += p2;
#pragma unroll
      for (int i = 0; i < 9; ++i) {
        float vv = Vt[j][d0 + i];
        O1[i] += p1 * vv;
        O2[i] += p2 * vv;
      }
    }
    m1 = nm1; m2 = nm2;
  }
  const float r1 = 1.0f / l1, r2 = 1.0f / l2;
#pragma unroll
  for (int i = 0; i < 9; ++i) {
    O[((size_t)(b * SEQ + q0 + q1)) * DMODEL + h * HEADDIM + d0 + i] = O1[i] * r1;
    O[((size_t)(b * SEQ + q0 + q2)) * DMODEL + h * HEADDIM + d0 + i] = O2[i] * r2;
  }
}

// ---------------- head attention-pooling (1 query/batch/head) ----------------
__global__ __launch_bounds__(256) void head_attn_kernel(
    const float* __restrict__ hq, const float* __restrict__ Kb,
    const float* __restrict__ Vb, const float* __restrict__ mask,
    float* __restrict__ hp)
{
  __shared__ float sc[SEQ];
  __shared__ float red[8];
  __shared__ float qv[HEADDIM];
  const int h = blockIdx.x, b = blockIdx.y, tid = threadIdx.x;
  const float scale = 0.11785113019775793f;
  if (tid < HEADDIM) qv[tid] = hq[h * HEADDIM + tid];
  __syncthreads();
  for (int j = tid; j < SEQ; j += 256) {
    const float* kr = Kb + ((size_t)(b * SEQ + j)) * DMODEL + h * HEADDIM;
    float s = 0.f;
    for (int d = 0; d < HEADDIM; ++d) s += qv[d] * kr[d];
    float ma = (1.0f - mask[b * SEQ + j]) * -3.4028234663852886e38f;
    sc[j] = s * scale + ma;
  }
  __syncthreads();
  float mx = -1e30f;
  for (int j = tid; j < SEQ; j += 256) mx = fmaxf(mx, sc[j]);
  for (int off = 32; off; off >>= 1) mx = fmaxf(mx, __shfl_down(mx, off));
  if ((tid & 63) == 0) red[tid >> 6] = mx;
  __syncthreads();
  mx = fmaxf(fmaxf(red[0], red[1]), fmaxf(red[2], red[3]));
  float sm = 0.f;
  for (int j = tid; j < SEQ; j += 256) { float p = __expf(sc[j] - mx); sc[j] = p; sm += p; }
  for (int off = 32; off; off >>= 1) sm += __shfl_down(sm, off);
  if ((tid & 63) == 0) red[4 + (tid >> 6)] = sm;
  __syncthreads();
  sm = red[4] + red[5] + red[6] + red[7];
  if (tid < HEADDIM) {
    float o = 0.f;
    for (int j = 0; j < SEQ; ++j)
      o += sc[j] * Vb[((size_t)(b * SEQ + j)) * DMODEL + h * HEADDIM + tid];
    hp[b * DMODEL + h * HEADDIM + tid] = o / sm;
  }
}

// ---------------- small fp32 GEMM for tiny-M head ops ----------------
// grid (ceil(N/256), M)
__global__ __launch_bounds__(256) void small_gemm(
    const float* __restrict__ A, const float* __restrict__ W,
    const float* __restrict__ bias, const float* __restrict__ R,
    float* __restrict__ C, int M, int N, int K, int mode)
{
  const int n = blockIdx.x * 256 + threadIdx.x;
  const int m = blockIdx.y;
  if (n >= N) return;
  float acc = 0.f;
  const float* ar = A + (size_t)m * K;
  for (int k = 0; k < K; ++k) acc += ar[k] * W[(size_t)k * N + n];
  acc += bias[n];
  if (mode == 1) acc += R[(size_t)m * N + n];
  else if (mode == 2) acc = gelu_tanh(acc);
  C[(size_t)m * N + n] = acc;
}

// ---------------- host orchestration ----------------
extern "C" void kernel_launch(void* const* d_in, const int* in_sizes, int n_in,
                              void* d_out, int out_size, void* d_ws, size_t ws_size,
                              hipStream_t stream) {
  (void)in_sizes; (void)n_in; (void)out_size; (void)ws_size;
  const float* pixel   = (const float*)d_in[0];
  const float* amask   = (const float*)d_in[1];
  const int*   sshapes = (const int*)d_in[2];
  const float* patch_w = (const float*)d_in[3];
  const float* patch_b = (const float*)d_in[4];
  const float* pos_emb = (const float*)d_in[5];
  const float* ln1_w   = (const float*)d_in[6];
  const float* ln1_b   = (const float*)d_in[7];
  const float* qw      = (const float*)d_in[8];
  const float* qb      = (const float*)d_in[9];
  const float* kw      = (const float*)d_in[10];
  const float* kb      = (const float*)d_in[11];
  const float* vw      = (const float*)d_in[12];
  const float* vb      = (const float*)d_in[13];
  const float* ow      = (const float*)d_in[14];
  const float* ob      = (const float*)d_in[15];
  const float* ln2_w   = (const float*)d_in[16];
  const float* ln2_b   = (const float*)d_in[17];
  const float* fc1_w   = (const float*)d_in[18];
  const float* fc1_b   = (const float*)d_in[19];
  const float* fc2_w   = (const float*)d_in[20];
  const float* fc2_b   = (const float*)d_in[21];
  const float* postw   = (const float*)d_in[22];
  const float* postb   = (const float*)d_in[23];
  const float* probe   = (const float*)d_in[24];
  const float* h_qw    = (const float*)d_in[25];
  const float* h_qb    = (const float*)d_in[26];
  const float* h_kw    = (const float*)d_in[27];
  const float* h_kb    = (const float*)d_in[28];
  const float* h_vw    = (const float*)d_in[29];
  const float* h_vb    = (const float*)d_in[30];
  const float* h_ow    = (const float*)d_in[31];
  const float* h_ob    = (const float*)d_in[32];
  const float* h_ln_w  = (const float*)d_in[33];
  const float* h_ln_b  = (const float*)d_in[34];
  const float* h_fc1_w = (const float*)d_in[35];
  const float* h_fc1_b = (const float*)d_in[36];
  const float* h_fc2_w = (const float*)d_in[37];
  const float* h_fc2_b = (const float*)d_in[38];

  const size_t NTOK = (size_t)BATCH * SEQ;           // 4096
  const size_t ACT  = NTOK * DMODEL;                 // 4,718,592 floats
  float* ws   = (float*)d_ws;
  float* hbuf = ws;                                  // hidden state
  float* xbuf = hbuf + ACT;                          // LN output
  float* qbuf = xbuf + ACT;
  float* kbuf = qbuf + ACT;
  float* vbuf = kbuf + ACT;
  float* abuf = vbuf + ACT;                          // attention output
  float* tbuf = qbuf;                                // FF intermediate, aliases q/k/v/a
  float* smal = abuf + ACT;                          // small head buffers
  float* hqv  = smal;                                // 1152
  float* hpb  = hqv + DMODEL;                        // 4x1152
  float* hp2  = hpb + BATCH * DMODEL;                // 4x1152
  float* hpn  = hp2 + BATCH * DMODEL;                // 4x1152
  float* htb  = hpn + BATCH * DMODEL;                // 4x4304

  float* out_last   = (float*)d_out;                 // (4,1024,1152)
  float* out_pooled = out_last + ACT;                // (4,1152)

  const dim3 blk(256);
  const dim3 gD((DMODEL + BN - 1) / BN, (NTOK + BM - 1) / BM);   // (9,32)
  const dim3 gF((FFDIM + BN - 1) / BN, (NTOK + BM - 1) / BM);    // (34,32)

  // patch embedding + resized positional embedding
  gemm_bf16<<<gD, blk, 0, stream>>>(pixel, patch_w, patch_b, nullptr, hbuf,
                                    (int)NTOK, DMODEL, PATCHIN, 0);
  pos_add_kernel<<<(int)NTOK, 288, 0, stream>>>(pos_emb, sshapes, hbuf);

  for (int l = 0; l < NLAYERS; ++l) {
    const size_t wo = (size_t)l * DMODEL * DMODEL;
    const size_t fo = (size_t)l * DMODEL * FFDIM;
    const size_t bo = (size_t)l * DMODEL;
    const size_t fb = (size_t)l * FFDIM;
    ln_kernel<<<(int)NTOK, blk, 0, stream>>>(hbuf, ln1_w + bo, ln1_b + bo, xbuf);
    gemm_bf16<<<gD, blk, 0, stream>>>(xbuf, qw + wo, qb + bo, nullptr, qbuf,
                                      (int)NTOK, DMODEL, DMODEL, 0);
    gemm_bf16<<<gD, blk, 0, stream>>>(xbuf, kw + wo, kb + bo, nullptr, kbuf,
                                      (int)NTOK, DMODEL, DMODEL, 0);
    gemm_bf16<<<gD, blk, 0, stream>>>(xbuf, vw + wo, vb + bo, nullptr, vbuf,
                                      (int)NTOK, DMODEL, DMODEL, 0);
    attn_kernel<<<dim3(SEQ / 64, NHEADS, BATCH), blk, 0, stream>>>(
        qbuf, kbuf, vbuf, amask, abuf);
    gemm_bf16<<<gD, blk, 0, stream>>>(abuf, ow + wo, ob + bo, hbuf, hbuf,
                                      (int)NTOK, DMODEL, DMODEL, 1);
    ln_kernel<<<(int)NTOK, blk, 0, stream>>>(hbuf, ln2_w + bo, ln2_b + bo, xbuf);
    gemm_bf16<<<gF, blk, 0, stream>>>(xbuf, fc1_w + fo, fc1_b + fb, nullptr, tbuf,
                                      (int)NTOK, FFDIM, DMODEL, 2);
    gemm_bf16<<<gD, blk, 0, stream>>>(tbuf, fc2_w + fo, fc2_b + bo, hbuf, hbuf,
                                      (int)NTOK, DMODEL, FFDIM, 1);
  }

  // post-LN -> first output; also the input to the pooling head
  ln_kernel<<<(int)NTOK, blk, 0, stream>>>(hbuf, postw, postb, out_last);

  // head K/V projections (M=4096 MFMA GEMMs)
  gemm_bf16<<<gD, blk, 0, stream>>>(out_last, h_kw, h_kb, nullptr, kbuf,
                                    (int)NTOK, DMODEL, DMODEL, 0);
  gemm_bf16<<<gD, blk, 0, stream>>>(out_last, h_vw, h_vb, nullptr, vbuf,
                                    (int)NTOK, DMODEL, DMODEL, 0);
  // probe query (same for all batches): (1,1152)
  small_gemm<<<dim3(5, 1), blk, 0, stream>>>(probe, h_qw, h_qb, nullptr, hqv,
                                             1, DMODEL, DMODEL, 0);
  head_attn_kernel<<<dim3(NHEADS, BATCH), blk, 0, stream>>>(hqv, kbuf, vbuf,
                                                            amask, hpb);
  small_gemm<<<dim3(5, BATCH), blk, 0, stream>>>(hpb, h_ow, h_ob, nullptr, hp2,
                                                 BATCH, DMODEL, DMODEL, 0);
  ln_kernel<<<BATCH, blk, 0, stream>>>(hp2, h_ln_w, h_ln_b, hpn);
  small_gemm<<<dim3(17, BATCH), blk, 0, stream>>>(hpn, h_fc1_w, h_fc1_b, nullptr,
                                                  htb, BATCH, FFDIM, DMODEL, 2);
  small_gemm<<<dim3(5, BATCH), blk, 0, stream>>>(htb, h_fc2_w, h_fc2_b, hp2,
                                                 out_pooled, BATCH, DMODEL, FFDIM, 1);
}

// Round 2
// 13288.965 us; speedup vs baseline: 1.2194x; 1.2194x over previous
//
#include <hip/hip_runtime.h>
#include <hip/hip_bf16.h>
#include <cstdint>
#include <cstddef>

// ---------------- problem constants ----------------
#define BATCH    4
#define SEQ      1024
#define DMODEL   1152
#define NHEADS   16
#define HEADDIM  72
#define FFDIM    4304
#define NLAYERS  6
#define PATCHIN  588
#define LN_EPS   1e-6f

typedef float f32x4 __attribute__((ext_vector_type(4)));
typedef __bf16 bf16x8 __attribute__((ext_vector_type(8)));
typedef short s16x8 __attribute__((ext_vector_type(8)));
typedef short s16x4 __attribute__((ext_vector_type(4)));

__device__ __forceinline__ short f2bf(float f) {
  // fp32 -> bf16 bits, round-to-nearest-even
  unsigned u = __builtin_bit_cast(unsigned, f);
  u = (u + 0x7fffu + ((u >> 16) & 1u)) >> 16;
  return (short)u;
}

__device__ __forceinline__ float gelu_tanh(float x) {
  const float c0 = 0.7978845608028654f, c1 = 0.044715f;
  return 0.5f * x * (1.0f + tanhf(c0 * (x + c1 * x * x * x)));
}

// ---------------- bf16 MFMA GEMM ----------------
// C[M,N] = epilogue(A[M,K] @ B[K,N] + bias), A/B fp32 row-major, converted to
// bf16 at LDS staging. mode: 0 = +bias, 1 = +bias+R (residual), 2 = gelu(+bias)
#define BM 128
#define BN 128
#define BK 32
#define LDP 40   // LDS row stride in shorts (pad 32->40; 80B row keeps 16B align)

__global__ __launch_bounds__(256) void gemm_bf16(
    const float* __restrict__ A, const float* __restrict__ Bm,
    const float* __restrict__ bias, const float* __restrict__ Rres,
    float* __restrict__ C, int M, int N, int K, int mode)
{
  __shared__ __align__(16) short As[BM * LDP];
  __shared__ __align__(16) short Bs[BN * LDP];
  const int tid = threadIdx.x;
  const int wave = tid >> 6, lane = tid & 63;
  const int lr = lane & 15, lq = lane >> 4;
  const int m0 = blockIdx.y * BM, n0 = blockIdx.x * BN;
  const int wm = (wave & 1) * 64, wn = (wave >> 1) * 64;

  f32x4 acc[4][4];
#pragma unroll
  for (int i = 0; i < 4; ++i)
#pragma unroll
    for (int j = 0; j < 4; ++j) acc[i][j] = (f32x4)(0.0f);

  const int nk = (K + BK - 1) / BK;
  for (int kt = 0; kt < nk; ++kt) {
    const int k0 = kt * BK;
    // --- stage A tile: 128 rows x 32 k (1024 float4 slots / 256 threads) ---
#pragma unroll
    for (int i = 0; i < 4; ++i) {
      int slot = tid + 256 * i;
      int row = slot >> 3, f4c = slot & 7;
      int gm = m0 + row, gk = k0 + f4c * 4;
      float4 v = make_float4(0.f, 0.f, 0.f, 0.f);
      if (gm < M) {
        const float* ar = A + (size_t)gm * K;
        if (gk + 3 < K) v = *(const float4*)(ar + gk);
        else {
          if (gk + 0 < K) v.x = ar[gk + 0];
          if (gk + 1 < K) v.y = ar[gk + 1];
          if (gk + 2 < K) v.z = ar[gk + 2];
          if (gk + 3 < K) v.w = ar[gk + 3];
        }
      }
      s16x4 sv = {f2bf(v.x), f2bf(v.y), f2bf(v.z), f2bf(v.w)};
      *(s16x4*)&As[row * LDP + f4c * 4] = sv;
    }
    // --- stage B tile transposed: Bs[n][k]; loads coalesced along n ---
#pragma unroll
    for (int i = 0; i < 4; ++i) {
      int slot = tid + 256 * i;
      int n = slot & 127, kq = slot >> 7;
      int gn = n0 + n;
      float v0 = 0.f, v1 = 0.f, v2 = 0.f, v3 = 0.f;
      if (gn < N) {
        int gk = k0 + kq * 4;
        const float* br = Bm + gn;
        if (gk + 0 < K) v0 = br[(size_t)(gk + 0) * N];
        if (gk + 1 < K) v1 = br[(size_t)(gk + 1) * N];
        if (gk + 2 < K) v2 = br[(size_t)(gk + 2) * N];
        if (gk + 3 < K) v3 = br[(size_t)(gk + 3) * N];
      }
      s16x4 sv = {f2bf(v0), f2bf(v1), f2bf(v2), f2bf(v3)};
      *(s16x4*)&Bs[n * LDP + kq * 4] = sv;
    }
    __syncthreads();
    // --- fragments + MFMA ---
    s16x8 af[4], bfr[4];
#pragma unroll
    for (int mi = 0; mi < 4; ++mi)
      af[mi] = *(const s16x8*)&As[(wm + mi * 16 + lr) * LDP + lq * 8];
#pragma unroll
    for (int ni = 0; ni < 4; ++ni)
      bfr[ni] = *(const s16x8*)&Bs[(wn + ni * 16 + lr) * LDP + lq * 8];
#pragma unroll
    for (int mi = 0; mi < 4; ++mi)
#pragma unroll
      for (int ni = 0; ni < 4; ++ni)
        acc[mi][ni] = __builtin_amdgcn_mfma_f32_16x16x32_bf16(
            __builtin_bit_cast(bf16x8, af[mi]),
            __builtin_bit_cast(bf16x8, bfr[ni]), acc[mi][ni], 0, 0, 0);
    __syncthreads();
  }
  // --- epilogue: D[row=(lane>>4)*4+r][col=lane&15] (m89-verified layout) ---
#pragma unroll
  for (int ni = 0; ni < 4; ++ni) {
    int col = n0 + wn + ni * 16 + lr;
    if (col >= N) continue;
    float bv = bias[col];
#pragma unroll
    for (int mi = 0; mi < 4; ++mi) {
#pragma unroll
      for (int r = 0; r < 4; ++r) {
        int row = m0 + wm + mi * 16 + lq * 4 + r;
        if (row >= M) continue;
        float v = acc[mi][ni][r] + bv;
        if (mode == 1) v += Rres[(size_t)row * N + col];
        else if (mode == 2) v = gelu_tanh(v);
        C[(size_t)row * N + col] = v;
      }
    }
  }
}

// ---------------- LayerNorm (rows of 1152) ----------------
__global__ __launch_bounds__(256) void ln_kernel(
    const float* __restrict__ in, const float* __restrict__ w,
    const float* __restrict__ b, float* __restrict__ out)
{
  const int row = blockIdx.x, tid = threadIdx.x;
  __shared__ float buf[DMODEL];
  __shared__ float red[8];
  const float* x = in + (size_t)row * DMODEL;
  float s = 0.f;
  for (int i = tid; i < DMODEL; i += 256) { float v = x[i]; buf[i] = v; s += v; }
  for (int off = 32; off; off >>= 1) s += __shfl_down(s, off);
  if ((tid & 63) == 0) red[tid >> 6] = s;
  __syncthreads();
  const float mean = (red[0] + red[1] + red[2] + red[3]) * (1.0f / DMODEL);
  float vs = 0.f;
  for (int i = tid; i < DMODEL; i += 256) { float d = buf[i] - mean; vs += d * d; }
  for (int off = 32; off; off >>= 1) vs += __shfl_down(vs, off);
  if ((tid & 63) == 0) red[4 + (tid >> 6)] = vs;
  __syncthreads();
  const float var = (red[4] + red[5] + red[6] + red[7]) * (1.0f / DMODEL);
  const float rstd = rsqrtf(var + LN_EPS);
  float* o = out + (size_t)row * DMODEL;
  for (int i = tid; i < DMODEL; i += 256)
    o[i] = (buf[i] - mean) * rstd * w[i] + b[i];
}

// ---------------- position-embedding bilinear resize + add ----------------
__global__ __launch_bounds__(288) void pos_add_kernel(
    const float* __restrict__ pos, const int* __restrict__ ssp,
    float* __restrict__ hbuf)
{
  const int bs = blockIdx.x;
  const int b = bs >> 10, s = bs & (SEQ - 1);
  int hs, wd;
  if (ssp[1] == 0 && ssp[3] == 0) { hs = ssp[b * 4]; wd = ssp[b * 4 + 2]; }
  else { hs = ssp[b * 2]; wd = ssp[b * 2 + 1]; }
  int r = 0, c = 0;
  if (s < hs * wd) { r = s / wd; c = s % wd; }
  const float fy = (r + 0.5f) * (16.0f / hs) - 0.5f;
  const float fx = (c + 0.5f) * (16.0f / wd) - 0.5f;
  const float y0f = floorf(fy), x0f = floorf(fx);
  const float ty = fy - y0f, tx = fx - x0f;
  const int y0 = (int)y0f, x0 = (int)x0f;
  const int y0c = min(max(y0, 0), 15), y1c = min(max(y0 + 1, 0), 15);
  const int x0c = min(max(x0, 0), 15), x1c = min(max(x0 + 1, 0), 15);
  const float w00 = (1.f - ty) * (1.f - tx), w01 = (1.f - ty) * tx;
  const float w10 = ty * (1.f - tx), w11 = ty * tx;
  const float* p00 = pos + (size_t)(y0c * 16 + x0c) * DMODEL;
  const float* p01 = pos + (size_t)(y0c * 16 + x1c) * DMODEL;
  const float* p10 = pos + (size_t)(y1c * 16 + x0c) * DMODEL;
  const float* p11 = pos + (size_t)(y1c * 16 + x1c) * DMODEL;
  float* hrow = hbuf + (size_t)bs * DMODEL;
  const int d0 = threadIdx.x * 4;
#pragma unroll
  for (int i = 0; i < 4; ++i) {
    int d = d0 + i;
    hrow[d] += w00 * p00[d] + w01 * p01[d] + w10 * p10[d] + w11 * p11[d];
  }
}

// ---------------- flash attention (fp32, online softmax) ----------------
__global__ __launch_bounds__(256) void attn_kernel(
    const float* __restrict__ Q, const float* __restrict__ Kb,
    const float* __restrict__ Vb, const float* __restrict__ mask,
    float* __restrict__ O)
{
  __shared__ __align__(16) float Qt[64][72];
  __shared__ __align__(16) float Kt[64][76];
  __shared__ __align__(16) float Vt[64][76];
  __shared__ float Ps[64][65];
  __shared__ float madd[64];
  const int tid = threadIdx.x;
  const int q0 = blockIdx.x * 64, h = blockIdx.y, b = blockIdx.z;
  const float scale = 0.11785113019775793f;    // 1/sqrt(72)

  for (int idx = tid; idx < 64 * 72; idx += 256) {
    int qi = idx / 72, d = idx % 72;
    Qt[qi][d] = Q[((size_t)(b * SEQ + q0 + qi)) * DMODEL + h * HEADDIM + d];
  }
  const int ds = tid & 7, d0 = ds * 9;
  const int qp = tid >> 3, q1 = qp * 2, q2 = qp * 2 + 1;
  const int jj = tid & 63, qoff = tid >> 6;
  float m1 = -1e30f, l1 = 0.f, m2 = -1e30f, l2 = 0.f;
  float O1[9], O2[9];
#pragma unroll
  for (int i = 0; i < 9; ++i) { O1[i] = 0.f; O2[i] = 0.f; }

  for (int kt = 0; kt < SEQ / 64; ++kt) {
    const int k0 = kt * 64;
    __syncthreads();
    for (int idx = tid; idx < 64 * 72; idx += 256) {
      int j = idx / 72, d = idx % 72;
      size_t base = ((size_t)(b * SEQ + k0 + j)) * DMODEL + h * HEADDIM + d;
      Kt[j][d] = Kb[base];
      Vt[j][d] = Vb[base];
    }
    if (tid < 64)
      madd[tid] = (1.0f - mask[b * SEQ + k0 + tid]) * -3.4028234663852886e38f;
    __syncthreads();
    {
      float accs[16];
#pragma unroll
      for (int ii = 0; ii < 16; ++ii) accs[ii] = 0.f;
      const float4* krow = (const float4*)&Kt[jj][0];
      for (int dq = 0; dq < 18; ++dq) {
        float4 kv = krow[dq];
#pragma unroll
        for (int ii = 0; ii < 16; ++ii) {
          const float4 qv = ((const float4*)&Qt[qoff + ii * 4][0])[dq];
          accs[ii] += kv.x * qv.x + kv.y * qv.y + kv.z * qv.z + kv.w * qv.w;
        }
      }
      float ma = madd[jj];
#pragma unroll
      for (int ii = 0; ii < 16; ++ii)
        Ps[qoff + ii * 4][jj] = accs[ii] * scale + ma;
    }
    __syncthreads();
    float tm1 = -1e30f, tm2 = -1e30f;
    for (int j = 0; j < 64; ++j) {
      tm1 = fmaxf(tm1, Ps[q1][j]);
      tm2 = fmaxf(tm2, Ps[q2][j]);
    }
    float nm1 = fmaxf(m1, tm1), nm2 = fmaxf(m2, tm2);
    float a1 = __expf(m1 - nm1), a2 = __expf(m2 - nm2);
#pragma unroll
    for (int i = 0; i < 9; ++i) { O1[i] *= a1; O2[i] *= a2; }
    l1 *= a1; l2 *= a2;
    for (int j = 0; j < 64; ++j) {
      float p1 = __expf(Ps[q1][j] - nm1);
      float p2 = __expf(Ps[q2][j] - nm2);
      l1 += p1; l2 += p2;
#pragma unroll
      for (int i = 0; i < 9; ++i) {
        float vv = Vt[j][d0 + i];
        O1[i] += p1 * vv;
        O2[i] += p2 * vv;
      }
    }
    m1 = nm1; m2 = nm2;
  }
  const float r1 = 1.0f / l1, r2 = 1.0f / l2;
#pragma unroll
  for (int i = 0; i < 9; ++i) {
    O[((size_t)(b * SEQ + q0 + q1)) * DMODEL + h * HEADDIM + d0 + i] = O1[i] * r1;
    O[((size_t)(b * SEQ + q0 + q2)) * DMODEL + h * HEADDIM + d0 + i] = O2[i] * r2;
  }
}

// ---------------- head attention-pooling (1 query/batch/head) ----------------
__global__ __launch_bounds__(256) void head_attn_kernel(
    const float* __restrict__ hq, const float* __restrict__ Kb,
    const float* __restrict__ Vb, const float* __restrict__ mask,
    float* __restrict__ hp)
{
  __shared__ float sc[SEQ];
  __shared__ float red[8];
  __shared__ float qv[HEADDIM];
  __shared__ float opart[3][HEADDIM];
  const int h = blockIdx.x, b = blockIdx.y, tid = threadIdx.x;
  const float scale = 0.11785113019775793f;
  if (tid < HEADDIM) qv[tid] = hq[h * HEADDIM + tid];
  __syncthreads();
  for (int j = tid; j < SEQ; j += 256) {
    const float* kr = Kb + ((size_t)(b * SEQ + j)) * DMODEL + h * HEADDIM;
    float s = 0.f;
    for (int d = 0; d < HEADDIM; ++d) s += qv[d] * kr[d];
    float ma = (1.0f - mask[b * SEQ + j]) * -3.4028234663852886e38f;
    sc[j] = s * scale + ma;
  }
  __syncthreads();
  float mx = -1e30f;
  for (int j = tid; j < SEQ; j += 256) mx = fmaxf(mx, sc[j]);
  for (int off = 32; off; off >>= 1) mx = fmaxf(mx, __shfl_down(mx, off));
  if ((tid & 63) == 0) red[tid >> 6] = mx;
  __syncthreads();
  mx = fmaxf(fmaxf(red[0], red[1]), fmaxf(red[2], red[3]));
  float sm = 0.f;
  for (int j = tid; j < SEQ; j += 256) { float p = __expf(sc[j] - mx); sc[j] = p; sm += p; }
  for (int off = 32; off; off >>= 1) sm += __shfl_down(sm, off);
  if ((tid & 63) == 0) red[4 + (tid >> 6)] = sm;
  __syncthreads();
  sm = red[4] + red[5] + red[6] + red[7];
  // PV: 216 threads = 3 j-phases x 72 dims, coalesced along d
  if (tid < 216) {
    const int d = tid % HEADDIM, js = tid / HEADDIM;
    float o = 0.f;
    for (int j = js; j < SEQ; j += 3)
      o += sc[j] * Vb[((size_t)(b * SEQ + j)) * DMODEL + h * HEADDIM + d];
    opart[js][d] = o;
  }
  __syncthreads();
  if (tid < HEADDIM)
    hp[b * DMODEL + h * HEADDIM + tid] =
        (opart[0][tid] + opart[1][tid] + opart[2][tid]) / sm;
}

// ---------------- split-K GEMV for tiny-M head GEMMs ----------------
// part[ks][m][n] = sum_{k in chunk ks} A[m][k] * W[k][n];  M <= 4
#define KSPLIT 16
#define KCMAX  272   // ceil(4304/16)=269, padded

__global__ __launch_bounds__(256) void gemv_splitk(
    const float* __restrict__ A, const float* __restrict__ W,
    float* __restrict__ part, int M, int N, int K)
{
  __shared__ float As[4 * KCMAX];
  const int tid = threadIdx.x;
  const int ks = blockIdx.y;
  const int kc = (K + KSPLIT - 1) / KSPLIT;
  const int k0 = ks * kc;
  const int len = min(K, k0 + kc) - k0;
  for (int i = tid; i < M * len; i += 256) {
    int m = i / len, k = i - m * len;
    As[m * KCMAX + k] = A[(size_t)m * K + k0 + k];
  }
  __syncthreads();
  const int n = blockIdx.x * 256 + tid;
  if (n >= N) return;
  const float* wp = W + (size_t)k0 * N + n;
  if (M == 1) {
    float a0 = 0.f;
#pragma unroll 4
    for (int k = 0; k < len; ++k) a0 += As[k] * wp[(size_t)k * N];
    part[(size_t)ks * N + n] = a0;
  } else {
    float a0 = 0.f, a1 = 0.f, a2 = 0.f, a3 = 0.f;
#pragma unroll 4
    for (int k = 0; k < len; ++k) {
      float w = wp[(size_t)k * N];
      a0 += As[0 * KCMAX + k] * w;
      a1 += As[1 * KCMAX + k] * w;
      a2 += As[2 * KCMAX + k] * w;
      a3 += As[3 * KCMAX + k] * w;
    }
    float* pb = part + (size_t)ks * 4 * N + n;
    pb[0 * N] = a0; pb[1 * N] = a1; pb[2 * N] = a2; pb[3 * N] = a3;
  }
}

__global__ __launch_bounds__(256) void gemv_reduce(
    const float* __restrict__ part, const float* __restrict__ bias,
    const float* __restrict__ R, float* __restrict__ C, int M, int N, int mode)
{
  const int n = blockIdx.x * 256 + threadIdx.x;
  const int m = blockIdx.y;
  if (n >= N) return;
  float s = 0.f;
#pragma unroll
  for (int ks = 0; ks < KSPLIT; ++ks) s += part[((size_t)ks * M + m) * N + n];
  s += bias[n];
  if (mode == 1) s += R[(size_t)m * N + n];
  else if (mode == 2) s = gelu_tanh(s);
  C[(size_t)m * N + n] = s;
}

// ---------------- host orchestration ----------------
extern "C" void kernel_launch(void* const* d_in, const int* in_sizes, int n_in,
                              void* d_out, int out_size, void* d_ws, size_t ws_size,
                              hipStream_t stream) {
  (void)in_sizes; (void)n_in; (void)out_size; (void)ws_size;
  const float* pixel   = (const float*)d_in[0];
  const float* amask   = (const float*)d_in[1];
  const int*   sshapes = (const int*)d_in[2];
  const float* patch_w = (const float*)d_in[3];
  const float* patch_b = (const float*)d_in[4];
  const float* pos_emb = (const float*)d_in[5];
  const float* ln1_w   = (const float*)d_in[6];
  const float* ln1_b   = (const float*)d_in[7];
  const float* qw      = (const float*)d_in[8];
  const float* qb      = (const float*)d_in[9];
  const float* kw      = (const float*)d_in[10];
  const float* kb      = (const float*)d_in[11];
  const float* vw      = (const float*)d_in[12];
  const float* vb      = (const float*)d_in[13];
  const float* ow      = (const float*)d_in[14];
  const float* ob      = (const float*)d_in[15];
  const float* ln2_w   = (const float*)d_in[16];
  const float* ln2_b   = (const float*)d_in[17];
  const float* fc1_w   = (const float*)d_in[18];
  const float* fc1_b   = (const float*)d_in[19];
  const float* fc2_w   = (const float*)d_in[20];
  const float* fc2_b   = (const float*)d_in[21];
  const float* postw   = (const float*)d_in[22];
  const float* postb   = (const float*)d_in[23];
  const float* probe   = (const float*)d_in[24];
  const float* h_qw    = (const float*)d_in[25];
  const float* h_qb    = (const float*)d_in[26];
  const float* h_kw    = (const float*)d_in[27];
  const float* h_kb    = (const float*)d_in[28];
  const float* h_vw    = (const float*)d_in[29];
  const float* h_vb    = (const float*)d_in[30];
  const float* h_ow    = (const float*)d_in[31];
  const float* h_ob    = (const float*)d_in[32];
  const float* h_ln_w  = (const float*)d_in[33];
  const float* h_ln_b  = (const float*)d_in[34];
  const float* h_fc1_w = (const float*)d_in[35];
  const float* h_fc1_b = (const float*)d_in[36];
  const float* h_fc2_w = (const float*)d_in[37];
  const float* h_fc2_b = (const float*)d_in[38];

  const size_t NTOK = (size_t)BATCH * SEQ;           // 4096
  const size_t ACT  = NTOK * DMODEL;                 // 4,718,592 floats
  float* ws   = (float*)d_ws;
  float* hbuf = ws;                                  // hidden state
  float* xbuf = hbuf + ACT;                          // LN output
  float* qbuf = xbuf + ACT;
  float* kbuf = qbuf + ACT;
  float* vbuf = kbuf + ACT;
  float* abuf = vbuf + ACT;                          // attention output
  float* tbuf = qbuf;                                // FF intermediate, aliases q/k/v/a
  float* smal = abuf + ACT;                          // small head buffers
  float* hqv  = smal;                                // 1152
  float* hpb  = hqv + DMODEL;                        // 4x1152
  float* hp2  = hpb + BATCH * DMODEL;                // 4x1152
  float* hpn  = hp2 + BATCH * DMODEL;                // 4x1152
  float* htb  = hpn + BATCH * DMODEL;                // 4x4304
  float* part = hbuf;   // split-K partials alias hbuf (dead after post-LN)

  float* out_last   = (float*)d_out;                 // (4,1024,1152)
  float* out_pooled = out_last + ACT;                // (4,1152)

  const dim3 blk(256);
  const dim3 gD((DMODEL + BN - 1) / BN, (NTOK + BM - 1) / BM);   // (9,32)
  const dim3 gF((FFDIM + BN - 1) / BN, (NTOK + BM - 1) / BM);    // (34,32)

  // patch embedding + resized positional embedding
  gemm_bf16<<<gD, blk, 0, stream>>>(pixel, patch_w, patch_b, nullptr, hbuf,
                                    (int)NTOK, DMODEL, PATCHIN, 0);
  pos_add_kernel<<<(int)NTOK, 288, 0, stream>>>(pos_emb, sshapes, hbuf);

  for (int l = 0; l < NLAYERS; ++l) {
    const size_t wo = (size_t)l * DMODEL * DMODEL;
    const size_t fo = (size_t)l * DMODEL * FFDIM;
    const size_t bo = (size_t)l * DMODEL;
    const size_t fb = (size_t)l * FFDIM;
    ln_kernel<<<(int)NTOK, blk, 0, stream>>>(hbuf, ln1_w + bo, ln1_b + bo, xbuf);
    gemm_bf16<<<gD, blk, 0, stream>>>(xbuf, qw + wo, qb + bo, nullptr, qbuf,
                                      (int)NTOK, DMODEL, DMODEL, 0);
    gemm_bf16<<<gD, blk, 0, stream>>>(xbuf, kw + wo, kb + bo, nullptr, kbuf,
                                      (int)NTOK, DMODEL, DMODEL, 0);
    gemm_bf16<<<gD, blk, 0, stream>>>(xbuf, vw + wo, vb + bo, nullptr, vbuf,
                                      (int)NTOK, DMODEL, DMODEL, 0);
    attn_kernel<<<dim3(SEQ / 64, NHEADS, BATCH), blk, 0, stream>>>(
        qbuf, kbuf, vbuf, amask, abuf);
    gemm_bf16<<<gD, blk, 0, stream>>>(abuf, ow + wo, ob + bo, hbuf, hbuf,
                                      (int)NTOK, DMODEL, DMODEL, 1);
    ln_kernel<<<(int)NTOK, blk, 0, stream>>>(hbuf, ln2_w + bo, ln2_b + bo, xbuf);
    gemm_bf16<<<gF, blk, 0, stream>>>(xbuf, fc1_w + fo, fc1_b + fb, nullptr, tbuf,
                                      (int)NTOK, FFDIM, DMODEL, 2);
    gemm_bf16<<<gD, blk, 0, stream>>>(tbuf, fc2_w + fo, fc2_b + bo, hbuf, hbuf,
                                      (int)NTOK, DMODEL, FFDIM, 1);
  }

  // post-LN -> first output; also the input to the pooling head
  ln_kernel<<<(int)NTOK, blk, 0, stream>>>(hbuf, postw, postb, out_last);

  // head K/V projections (M=4096 MFMA GEMMs)
  gemm_bf16<<<gD, blk, 0, stream>>>(out_last, h_kw, h_kb, nullptr, kbuf,
                                    (int)NTOK, DMODEL, DMODEL, 0);
  gemm_bf16<<<gD, blk, 0, stream>>>(out_last, h_vw, h_vb, nullptr, vbuf,
                                    (int)NTOK, DMODEL, DMODEL, 0);

  // ----- head (split-K GEMVs; `part` aliases dead hbuf) -----
  const dim3 gv5(5, KSPLIT), gv17(17, KSPLIT);
  // probe query: (1,1152) @ (1152,1152)
  gemv_splitk<<<gv5, blk, 0, stream>>>(probe, h_qw, part, 1, DMODEL, DMODEL);
  gemv_reduce<<<dim3(5, 1), blk, 0, stream>>>(part, h_qb, nullptr, hqv,
                                              1, DMODEL, 0);
  head_attn_kernel<<<dim3(NHEADS, BATCH), blk, 0, stream>>>(hqv, kbuf, vbuf,
                                                            amask, hpb);
  // hp2 = hpb @ h_ow + h_ob
  gemv_splitk<<<gv5, blk, 0, stream>>>(hpb, h_ow, part, BATCH, DMODEL, DMODEL);
  gemv_reduce<<<dim3(5, BATCH), blk, 0, stream>>>(part, h_ob, nullptr, hp2,
                                                  BATCH, DMODEL, 0);
  ln_kernel<<<BATCH, blk, 0, stream>>>(hp2, h_ln_w, h_ln_b, hpn);
  // htb = gelu(hpn @ h_fc1_w + h_fc1_b)
  gemv_splitk<<<gv17, blk, 0, stream>>>(hpn, h_fc1_w, part, BATCH, FFDIM, DMODEL);
  gemv_reduce<<<dim3(17, BATCH), blk, 0, stream>>>(part, h_fc1_b, nullptr, htb,
                                                   BATCH, FFDIM, 2);
  // pooled = htb @ h_fc2_w + h_fc2_b + hp2
  gemv_splitk<<<gv5, blk, 0, stream>>>(htb, h_fc2_w, part, BATCH, DMODEL, FFDIM);
  gemv_reduce<<<dim3(5, BATCH), blk, 0, stream>>>(part, h_fc2_b, hp2, out_pooled,
                                                  BATCH, DMODEL, 1);
}

// Round 3
// 5854.010 us; speedup vs baseline: 2.7682x; 2.2701x over previous
//
#include <hip/hip_runtime.h>
#include <hip/hip_bf16.h>
#include <cstdint>
#include <cstddef>

// ---------------- problem constants ----------------
#define BATCH    4
#define SEQ      1024
#define DMODEL   1152
#define NHEADS   16
#define HEADDIM  72
#define FFDIM    4304
#define NLAYERS  6
#define PATCHIN  588
#define LN_EPS   1e-6f

typedef float f32x4 __attribute__((ext_vector_type(4)));
typedef __bf16 bf16x8 __attribute__((ext_vector_type(8)));
typedef short s16x8 __attribute__((ext_vector_type(8)));

__device__ __forceinline__ unsigned short f2bf(float f) {
  unsigned u = __builtin_bit_cast(unsigned, f);
  u = (u + 0x7fffu + ((u >> 16) & 1u)) >> 16;
  return (unsigned short)u;
}
__device__ __forceinline__ float bfu2f(unsigned short u) {
  return __builtin_bit_cast(float, (unsigned)u << 16);
}
__device__ __forceinline__ float gelu_tanh(float x) {
  const float c0 = 0.7978845608028654f, c1 = 0.044715f;
  return 0.5f * x * (1.0f + tanhf(c0 * (x + c1 * x * x * x)));
}
__device__ __forceinline__ void gload16(const unsigned short* g, unsigned short* l) {
  __builtin_amdgcn_global_load_lds(
      (__attribute__((address_space(1))) void*)g,
      (__attribute__((address_space(3))) void*)l, 16, 0, 0);
}

// ---------------- bf16 MFMA GEMM, B^T weights, global_load_lds staging ------
// C[M,N] = epi(A[M,K] @ BT[N,K]^T + bias). A,BT bf16 row-major, K%32==0.
// mode: 0=+bias, 1=+bias+Rres(f32), 2=gelu(+bias). outbf: 1 -> bf16 C.
__global__ __launch_bounds__(256) void gemm_bt(
    const unsigned short* __restrict__ A, const unsigned short* __restrict__ BT,
    const float* __restrict__ bias, const float* __restrict__ Rres,
    void* __restrict__ Cout, int M, int N, int K, int ldc, int Nzero,
    int mode, int outbf)
{
  __shared__ __align__(16) unsigned short As[128 * 32];  // 8 KB, unpadded
  __shared__ __align__(16) unsigned short Bs[128 * 32];
  const int tid = threadIdx.x;
  const int wave = tid >> 6, lane = tid & 63;
  const int lr = lane & 15, lq = lane >> 4;
  const int m0 = blockIdx.y * 128, n0 = blockIdx.x * 128;
  const int wm = (wave & 1) * 64, wn = (wave >> 1) * 64;

  // staging map: slot s in {tid, tid+256}; row = s>>2, kchunk = s&3 (8 bf16).
  const int rowA = tid >> 2, kc = tid & 3;
  const unsigned short* gA0 = A + (size_t)(m0 + rowA) * K + kc * 8;
  const unsigned short* gA1 = gA0 + (size_t)64 * K;
  const int rB0 = min(n0 + rowA, N - 1);        // clamp tail (discarded cols)
  const int rB1 = min(n0 + rowA + 64, N - 1);
  const unsigned short* gB0 = BT + (size_t)rB0 * K + kc * 8;
  const unsigned short* gB1 = BT + (size_t)rB1 * K + kc * 8;
  unsigned short* lA0 = &As[tid * 8];
  unsigned short* lA1 = &As[(tid + 256) * 8];
  unsigned short* lB0 = &Bs[tid * 8];
  unsigned short* lB1 = &Bs[(tid + 256) * 8];

  f32x4 acc[4][4];
#pragma unroll
  for (int i = 0; i < 4; ++i)
#pragma unroll
    for (int j = 0; j < 4; ++j) acc[i][j] = (f32x4)(0.0f);

  for (int k0 = 0; k0 < K; k0 += 32) {
    gload16(gA0 + k0, lA0);
    gload16(gA1 + k0, lA1);
    gload16(gB0 + k0, lB0);
    gload16(gB1 + k0, lB1);
    __syncthreads();
    s16x8 af[4], bfr[4];
#pragma unroll
    for (int mi = 0; mi < 4; ++mi)
      af[mi] = *(const s16x8*)&As[(wm + mi * 16 + lr) * 32 + lq * 8];
#pragma unroll
    for (int ni = 0; ni < 4; ++ni)
      bfr[ni] = *(const s16x8*)&Bs[(wn + ni * 16 + lr) * 32 + lq * 8];
#pragma unroll
    for (int mi = 0; mi < 4; ++mi)
#pragma unroll
      for (int ni = 0; ni < 4; ++ni)
        acc[mi][ni] = __builtin_amdgcn_mfma_f32_16x16x32_bf16(
            __builtin_bit_cast(bf16x8, af[mi]),
            __builtin_bit_cast(bf16x8, bfr[ni]), acc[mi][ni], 0, 0, 0);
    __syncthreads();
  }
  // epilogue: D[row=(lane>>4)*4+r][col=lane&15]  (verified layout)
  unsigned short* cb = (unsigned short*)Cout;
  float* cf = (float*)Cout;
#pragma unroll
  for (int ni = 0; ni < 4; ++ni) {
    const int col = n0 + wn + ni * 16 + lr;
    if (col < N) {
      const float bv = bias[col];
#pragma unroll
      for (int mi = 0; mi < 4; ++mi)
#pragma unroll
        for (int r = 0; r < 4; ++r) {
          const int row = m0 + wm + mi * 16 + lq * 4 + r;
          float v = acc[mi][ni][r] + bv;
          if (mode == 1) v += Rres[(size_t)row * ldc + col];
          else if (mode == 2) v = gelu_tanh(v);
          if (outbf) cb[(size_t)row * ldc + col] = f2bf(v);
          else cf[(size_t)row * ldc + col] = v;
        }
    } else if (col < Nzero) {   // zero-fill K-padding columns (bf16 out only)
#pragma unroll
      for (int mi = 0; mi < 4; ++mi)
#pragma unroll
        for (int r = 0; r < 4; ++r) {
          const int row = m0 + wm + mi * 16 + lq * 4 + r;
          cb[(size_t)row * ldc + col] = 0;
        }
    }
  }
}

// ---------------- weight transpose + fp32->bf16 convert ----------------
// W[K][N] f32  ->  WT[N][KP] bf16, zero-padded for k in [K,KP). KP%32==0.
__global__ __launch_bounds__(256) void transpose_cvt(
    const float* __restrict__ W, unsigned short* __restrict__ WT,
    int K, int N, int KP)
{
  __shared__ float t[32][33];
  const int n0 = blockIdx.x * 32, k0 = blockIdx.y * 32;
  const int tx = threadIdx.x, ty = threadIdx.y;
#pragma unroll
  for (int i = 0; i < 32; i += 8) {
    const int k = k0 + ty + i, n = n0 + tx;
    t[ty + i][tx] = (k < K && n < N) ? W[(size_t)k * N + n] : 0.f;
  }
  __syncthreads();
#pragma unroll
  for (int i = 0; i < 32; i += 8) {
    const int n = n0 + ty + i, k = k0 + tx;
    if (n < N) WT[(size_t)n * KP + k] = f2bf(t[tx][ty + i]);
  }
}

// ---------------- pixel f32 -> bf16 with K-pad 588->608 ----------------
__global__ __launch_bounds__(256) void cvt_pixel(
    const float* __restrict__ P, unsigned short* __restrict__ Pb)
{
  const int col = blockIdx.x * 256 + threadIdx.x;
  const int row = blockIdx.y;
  if (col < 608) {
    const float v = (col < PATCHIN) ? P[(size_t)row * PATCHIN + col] : 0.f;
    Pb[(size_t)row * 608 + col] = f2bf(v);
  }
}

__global__ __launch_bounds__(256) void concat3(
    const float* __restrict__ a, const float* __restrict__ b,
    const float* __restrict__ c, float* __restrict__ o, int n)
{
  const int i = blockIdx.x * 256 + threadIdx.x;
  if (i < n) { o[i] = a[i]; o[n + i] = b[i]; o[2 * n + i] = c[i]; }
}

// ---------------- LayerNorm rows of 1152: f32 in, f32/bf16 out ----------
__global__ __launch_bounds__(256) void ln_kernel(
    const float* __restrict__ in, const float* __restrict__ w,
    const float* __restrict__ b, float* __restrict__ of32,
    unsigned short* __restrict__ ob16)
{
  const int row = blockIdx.x, tid = threadIdx.x;
  __shared__ float red[8];
  const float4* x4 = (const float4*)(in + (size_t)row * DMODEL);
  const bool has2 = tid < 32;                 // 288 float4 = 256 + 32
  float4 v0 = x4[tid];
  float4 v1 = has2 ? x4[256 + tid] : make_float4(0.f, 0.f, 0.f, 0.f);
  float s = v0.x + v0.y + v0.z + v0.w + v1.x + v1.y + v1.z + v1.w;
  for (int off = 32; off; off >>= 1) s += __shfl_down(s, off);
  if ((tid & 63) == 0) red[tid >> 6] = s;
  __syncthreads();
  const float mean = (red[0] + red[1] + red[2] + red[3]) * (1.0f / DMODEL);
  float vs = (v0.x - mean) * (v0.x - mean) + (v0.y - mean) * (v0.y - mean)
           + (v0.z - mean) * (v0.z - mean) + (v0.w - mean) * (v0.w - mean);
  if (has2)
    vs += (v1.x - mean) * (v1.x - mean) + (v1.y - mean) * (v1.y - mean)
        + (v1.z - mean) * (v1.z - mean) + (v1.w - mean) * (v1.w - mean);
  for (int off = 32; off; off >>= 1) vs += __shfl_down(vs, off);
  if ((tid & 63) == 0) red[4 + (tid >> 6)] = vs;
  __syncthreads();
  const float var = (red[4] + red[5] + red[6] + red[7]) * (1.0f / DMODEL);
  const float rstd = rsqrtf(var + LN_EPS);
  const float4* w4 = (const float4*)w;
  const float4* b4 = (const float4*)b;
  {
    float4 ww = w4[tid], bb = b4[tid], o;
    o.x = (v0.x - mean) * rstd * ww.x + bb.x;
    o.y = (v0.y - mean) * rstd * ww.y + bb.y;
    o.z = (v0.z - mean) * rstd * ww.z + bb.z;
    o.w = (v0.w - mean) * rstd * ww.w + bb.w;
    if (of32) ((float4*)(of32 + (size_t)row * DMODEL))[tid] = o;
    if (ob16) {
      ushort4 u; u.x = f2bf(o.x); u.y = f2bf(o.y); u.z = f2bf(o.z); u.w = f2bf(o.w);
      ((ushort4*)(ob16 + (size_t)row * DMODEL))[tid] = u;
    }
  }
  if (has2) {
    float4 ww = w4[256 + tid], bb = b4[256 + tid], o;
    o.x = (v1.x - mean) * rstd * ww.x + bb.x;
    o.y = (v1.y - mean) * rstd * ww.y + bb.y;
    o.z = (v1.z - mean) * rstd * ww.z + bb.z;
    o.w = (v1.w - mean) * rstd * ww.w + bb.w;
    if (of32) ((float4*)(of32 + (size_t)row * DMODEL))[256 + tid] = o;
    if (ob16) {
      ushort4 u; u.x = f2bf(o.x); u.y = f2bf(o.y); u.z = f2bf(o.z); u.w = f2bf(o.w);
      ((ushort4*)(ob16 + (size_t)row * DMODEL))[256 + tid] = u;
    }
  }
}

// ---------------- position-embedding bilinear resize + add (f32) --------
__global__ __launch_bounds__(288) void pos_add_kernel(
    const float* __restrict__ pos, const int* __restrict__ ssp,
    float* __restrict__ hbuf)
{
  const int bs = blockIdx.x;
  const int b = bs >> 10, s = bs & (SEQ - 1);
  int hs, wd;
  if (ssp[1] == 0 && ssp[3] == 0) { hs = ssp[b * 4]; wd = ssp[b * 4 + 2]; }
  else { hs = ssp[b * 2]; wd = ssp[b * 2 + 1]; }
  int r = 0, c = 0;
  if (s < hs * wd) { r = s / wd; c = s % wd; }
  const float fy = (r + 0.5f) * (16.0f / hs) - 0.5f;
  const float fx = (c + 0.5f) * (16.0f / wd) - 0.5f;
  const float y0f = floorf(fy), x0f = floorf(fx);
  const float ty = fy - y0f, tx = fx - x0f;
  const int y0 = (int)y0f, x0 = (int)x0f;
  const int y0c = min(max(y0, 0), 15), y1c = min(max(y0 + 1, 0), 15);
  const int x0c = min(max(x0, 0), 15), x1c = min(max(x0 + 1, 0), 15);
  const float w00 = (1.f - ty) * (1.f - tx), w01 = (1.f - ty) * tx;
  const float w10 = ty * (1.f - tx), w11 = ty * tx;
  const float* p00 = pos + (size_t)(y0c * 16 + x0c) * DMODEL;
  const float* p01 = pos + (size_t)(y0c * 16 + x1c) * DMODEL;
  const float* p10 = pos + (size_t)(y1c * 16 + x0c) * DMODEL;
  const float* p11 = pos + (size_t)(y1c * 16 + x1c) * DMODEL;
  float* hrow = hbuf + (size_t)bs * DMODEL;
  const int d0 = threadIdx.x * 4;
#pragma unroll
  for (int i = 0; i < 4; ++i) {
    const int d = d0 + i;
    hrow[d] += w00 * p00[d] + w01 * p01[d] + w10 * p10[d] + w11 * p11[d];
  }
}

// ---------------- flash attention, bf16 fused-QKV in, bf16 out ----------
// grid (SEQ/64, NHEADS, BATCH). Dedup softmax: 4 lanes per row (intra-wave).
__global__ __launch_bounds__(256) void attn_kernel(
    const unsigned short* __restrict__ QKV, const float* __restrict__ mask,
    unsigned short* __restrict__ Oa)
{
  __shared__ __align__(16) float Qt[64][72];
  __shared__ __align__(16) float Kt[64][76];
  __shared__ __align__(16) float VtT[72][68];   // V transposed: [d][j]
  __shared__ __align__(16) float Ps[64][68];
  __shared__ float rmax[64][4], rsum[64][4];
  __shared__ float m_row[64], l_row[64], alpha_row[64], madd[64];
  const int tid = threadIdx.x;
  const int q0 = blockIdx.x * 64, h = blockIdx.y, b = blockIdx.z;
  const float scale = 0.11785113019775793f;     // 1/sqrt(72)

  for (int idx = tid; idx < 64 * 18; idx += 256) {
    const int qi = idx / 18, g = idx % 18;
    const ushort4 raw = *(const ushort4*)(
        QKV + ((size_t)(b * SEQ + q0 + qi)) * 3456 + h * HEADDIM + g * 4);
    Qt[qi][g * 4 + 0] = bfu2f(raw.x);
    Qt[qi][g * 4 + 1] = bfu2f(raw.y);
    Qt[qi][g * 4 + 2] = bfu2f(raw.z);
    Qt[qi][g * 4 + 3] = bfu2f(raw.w);
  }
  if (tid < 64) { m_row[tid] = -1e30f; l_row[tid] = 0.f; }

  const int jj = tid & 63, qoff = tid >> 6;     // phase1: wave=qoff, lane=key
  const int r2 = tid >> 2, c4 = tid & 3;        // phase2: 4 lanes per row
  const int qp = tid >> 3, ds = tid & 7;        // PV: 2 rows x 9 dims
  const int q1 = qp * 2, q2 = qp * 2 + 1, d0 = ds * 9;
  float O1[9], O2[9];
#pragma unroll
  for (int i = 0; i < 9; ++i) { O1[i] = 0.f; O2[i] = 0.f; }

  for (int kt = 0; kt < SEQ / 64; ++kt) {
    const int k0 = kt * 64;
    __syncthreads();    // prior consumers of Kt/VtT/Ps done (also Q/m/l init)
    for (int idx = tid; idx < 64 * 18; idx += 256) {
      const int j = idx / 18, g = idx % 18;
      const size_t base = ((size_t)(b * SEQ + k0 + j)) * 3456 + h * HEADDIM + g * 4;
      const ushort4 kr = *(const ushort4*)(QKV + base + 1152);
      const ushort4 vr = *(const ushort4*)(QKV + base + 2304);
      Kt[j][g * 4 + 0] = bfu2f(kr.x);
      Kt[j][g * 4 + 1] = bfu2f(kr.y);
      Kt[j][g * 4 + 2] = bfu2f(kr.z);
      Kt[j][g * 4 + 3] = bfu2f(kr.w);
      VtT[g * 4 + 0][j] = bfu2f(vr.x);
      VtT[g * 4 + 1][j] = bfu2f(vr.y);
      VtT[g * 4 + 2][j] = bfu2f(vr.z);
      VtT[g * 4 + 3][j] = bfu2f(vr.w);
    }
    if (tid < 64)
      madd[tid] = (1.0f - mask[b * SEQ + k0 + tid]) * -3.4028234663852886e38f;
    __syncthreads();
    // phase1: scores. Q reads are wave-uniform (broadcast); K per-lane.
    {
      float accs[16];
#pragma unroll
      for (int ii = 0; ii < 16; ++ii) accs[ii] = 0.f;
      const float4* krow = (const float4*)&Kt[jj][0];
      for (int dq = 0; dq < 18; ++dq) {
        const float4 kv = krow[dq];
#pragma unroll
        for (int ii = 0; ii < 16; ++ii) {
          const float4 qv = ((const float4*)&Qt[qoff + ii * 4][0])[dq];
          accs[ii] += kv.x * qv.x + kv.y * qv.y + kv.z * qv.z + kv.w * qv.w;
        }
      }
      const float ma = madd[jj];
#pragma unroll
      for (int ii = 0; ii < 16; ++ii)
        Ps[qoff + ii * 4][jj] = accs[ii] * scale + ma;
    }
    __syncthreads();
    // phase2: row max / exp / sum. Wave w owns rows [16w,16w+16) -> all
    // cross-lane traffic below is intra-wave (in-order LDS), no barriers.
    {
      const float4* pr = (const float4*)&Ps[r2][0];
      float tmax = -1e30f;
#pragma unroll
      for (int g4 = 0; g4 < 4; ++g4) {
        const float4 p = pr[c4 * 4 + g4];
        tmax = fmaxf(tmax, fmaxf(fmaxf(p.x, p.y), fmaxf(p.z, p.w)));
      }
      rmax[r2][c4] = tmax;
      const float mold = m_row[r2];
      const float rm = fmaxf(fmaxf(rmax[r2][0], rmax[r2][1]),
                             fmaxf(rmax[r2][2], rmax[r2][3]));
      const float nm = fmaxf(mold, rm);
      const float alpha = __expf(mold - nm);
      float ls = 0.f;
      float* pw = &Ps[r2][c4 * 16];
#pragma unroll
      for (int j = 0; j < 16; ++j) {
        const float p = __expf(pw[j] - nm);
        pw[j] = p;
        ls += p;
      }
      rsum[r2][c4] = ls;
      if (c4 == 0) {
        m_row[r2] = nm;
        alpha_row[r2] = alpha;
        l_row[r2] = l_row[r2] * alpha +
                    (rsum[r2][0] + rsum[r2][1] + rsum[r2][2] + rsum[r2][3]);
      }
    }
    // PV: rows q1,q2 in [16w,16w+16) -> intra-wave dep on phase2, no barrier.
    {
      const float al1 = alpha_row[q1], al2 = alpha_row[q2];
#pragma unroll
      for (int i = 0; i < 9; ++i) { O1[i] *= al1; O2[i] *= al2; }
      const float4* p1r = (const float4*)&Ps[q1][0];
      const float4* p2r = (const float4*)&Ps[q2][0];
      for (int jq = 0; jq < 16; ++jq) {
        const float4 p1 = p1r[jq], p2 = p2r[jq];
#pragma unroll
        for (int i = 0; i < 9; ++i) {
          const float4 vv = ((const float4*)&VtT[d0 + i][0])[jq];
          O1[i] += p1.x * vv.x + p1.y * vv.y + p1.z * vv.z + p1.w * vv.w;
          O2[i] += p2.x * vv.x + p2.y * vv.y + p2.z * vv.z + p2.w * vv.w;
        }
      }
    }
  }
  const float rl1 = 1.0f / l_row[q1], rl2 = 1.0f / l_row[q2];
  unsigned short* ob1 = Oa + ((size_t)(b * SEQ + q0 + q1)) * DMODEL + h * HEADDIM + d0;
  unsigned short* ob2 = Oa + ((size_t)(b * SEQ + q0 + q2)) * DMODEL + h * HEADDIM + d0;
#pragma unroll
  for (int i = 0; i < 9; ++i) {
    ob1[i] = f2bf(O1[i] * rl1);
    ob2[i] = f2bf(O2[i] * rl2);
  }
}

// ---------------- head attention-pooling (bf16 K/V) ----------------
__global__ __launch_bounds__(256) void head_attn_kernel(
    const float* __restrict__ hq, const unsigned short* __restrict__ Kb,
    const unsigned short* __restrict__ Vb, const float* __restrict__ mask,
    float* __restrict__ hp)
{
  __shared__ float sc[SEQ];
  __shared__ float red[8];
  __shared__ float qv[HEADDIM];
  __shared__ float opart[3][HEADDIM];
  const int h = blockIdx.x, b = blockIdx.y, tid = threadIdx.x;
  const float scale = 0.11785113019775793f;
  if (tid < HEADDIM) qv[tid] = hq[h * HEADDIM + tid];
  __syncthreads();
  for (int j = tid; j < SEQ; j += 256) {
    const ushort4* kr4 = (const ushort4*)(
        Kb + ((size_t)(b * SEQ + j)) * DMODEL + h * HEADDIM);
    float s = 0.f;
#pragma unroll
    for (int g = 0; g < 18; ++g) {
      const ushort4 r4 = kr4[g];
      s += qv[g * 4 + 0] * bfu2f(r4.x) + qv[g * 4 + 1] * bfu2f(r4.y)
         + qv[g * 4 + 2] * bfu2f(r4.z) + qv[g * 4 + 3] * bfu2f(r4.w);
    }
    const float ma = (1.0f - mask[b * SEQ + j]) * -3.4028234663852886e38f;
    sc[j] = s * scale + ma;
  }
  __syncthreads();
  float mx = -1e30f;
  for (int j = tid; j < SEQ; j += 256) mx = fmaxf(mx, sc[j]);
  for (int off = 32; off; off >>= 1) mx = fmaxf(mx, __shfl_down(mx, off));
  if ((tid & 63) == 0) red[tid >> 6] = mx;
  __syncthreads();
  mx = fmaxf(fmaxf(red[0], red[1]), fmaxf(red[2], red[3]));
  float sm = 0.f;
  for (int j = tid; j < SEQ; j += 256) { float p = __expf(sc[j] - mx); sc[j] = p; sm += p; }
  for (int off = 32; off; off >>= 1) sm += __shfl_down(sm, off);
  if ((tid & 63) == 0) red[4 + (tid >> 6)] = sm;
  __syncthreads();
  sm = red[4] + red[5] + red[6] + red[7];
  if (tid < 216) {
    const int d = tid % HEADDIM, js = tid / HEADDIM;
    float o = 0.f;
    for (int j = js; j < SEQ; j += 3)
      o += sc[j] * bfu2f(Vb[((size_t)(b * SEQ + j)) * DMODEL + h * HEADDIM + d]);
    opart[js][d] = o;
  }
  __syncthreads();
  if (tid < HEADDIM)
    hp[b * DMODEL + h * HEADDIM + tid] =
        (opart[0][tid] + opart[1][tid] + opart[2][tid]) / sm;
}

// ---------------- split-K GEMV for tiny-M head GEMMs (f32 weights) -------
#define KSPLIT 16
#define KCMAX  272

__global__ __launch_bounds__(256) void gemv_splitk(
    const float* __restrict__ A, const float* __restrict__ W,
    float* __restrict__ part, int M, int N, int K)
{
  __shared__ float As[4 * KCMAX];
  const int tid = threadIdx.x;
  const int ks = blockIdx.y;
  const int kc = (K + KSPLIT - 1) / KSPLIT;
  const int k0 = ks * kc;
  const int len = min(K, k0 + kc) - k0;
  for (int i = tid; i < M * len; i += 256) {
    const int m = i / len, k = i - m * len;
    As[m * KCMAX + k] = A[(size_t)m * K + k0 + k];
  }
  __syncthreads();
  const int n = blockIdx.x * 256 + tid;
  if (n >= N) return;
  const float* wp = W + (size_t)k0 * N + n;
  if (M == 1) {
    float a0 = 0.f;
#pragma unroll 4
    for (int k = 0; k < len; ++k) a0 += As[k] * wp[(size_t)k * N];
    part[(size_t)ks * N + n] = a0;
  } else {
    float a0 = 0.f, a1 = 0.f, a2 = 0.f, a3 = 0.f;
#pragma unroll 4
    for (int k = 0; k < len; ++k) {
      const float w = wp[(size_t)k * N];
      a0 += As[0 * KCMAX + k] * w;
      a1 += As[1 * KCMAX + k] * w;
      a2 += As[2 * KCMAX + k] * w;
      a3 += As[3 * KCMAX + k] * w;
    }
    float* pb = part + (size_t)ks * 4 * N + n;
    pb[0 * N] = a0; pb[1 * N] = a1; pb[2 * N] = a2; pb[3 * N] = a3;
  }
}

__global__ __launch_bounds__(256) void gemv_reduce(
    const float* __restrict__ part, const float* __restrict__ bias,
    const float* __restrict__ R, float* __restrict__ C, int M, int N, int mode)
{
  const int n = blockIdx.x * 256 + threadIdx.x;
  const int m = blockIdx.y;
  if (n >= N) return;
  float s = 0.f;
#pragma unroll
  for (int ks = 0; ks < KSPLIT; ++ks) s += part[((size_t)ks * M + m) * N + n];
  s += bias[n];
  if (mode == 1) s += R[(size_t)m * N + n];
  else if (mode == 2) s = gelu_tanh(s);
  C[(size_t)m * N + n] = s;
}

// ---------------- host orchestration ----------------
extern "C" void kernel_launch(void* const* d_in, const int* in_sizes, int n_in,
                              void* d_out, int out_size, void* d_ws, size_t ws_size,
                              hipStream_t stream) {
  (void)in_sizes; (void)n_in; (void)out_size; (void)ws_size;
  const float* pixel   = (const float*)d_in[0];
  const float* amask   = (const float*)d_in[1];
  const int*   sshapes = (const int*)d_in[2];
  const float* patch_w = (const float*)d_in[3];
  const float* patch_b = (const float*)d_in[4];
  const float* pos_emb = (const float*)d_in[5];
  const float* ln1_w   = (const float*)d_in[6];
  const float* ln1_b   = (const float*)d_in[7];
  const float* qw      = (const float*)d_in[8];
  const float* qb      = (const float*)d_in[9];
  const float* kw      = (const float*)d_in[10];
  const float* kb      = (const float*)d_in[11];
  const float* vw      = (const float*)d_in[12];
  const float* vb      = (const float*)d_in[13];
  const float* ow      = (const float*)d_in[14];
  const float* ob      = (const float*)d_in[15];
  const float* ln2_w   = (const float*)d_in[16];
  const float* ln2_b   = (const float*)d_in[17];
  const float* fc1_w   = (const float*)d_in[18];
  const float* fc1_b   = (const float*)d_in[19];
  const float* fc2_w   = (const float*)d_in[20];
  const float* fc2_b   = (const float*)d_in[21];
  const float* postw   = (const float*)d_in[22];
  const float* postb   = (const float*)d_in[23];
  const float* probe   = (const float*)d_in[24];
  const float* h_qw    = (const float*)d_in[25];
  const float* h_qb    = (const float*)d_in[26];
  const float* h_kw    = (const float*)d_in[27];
  const float* h_kb    = (const float*)d_in[28];
  const float* h_vw    = (const float*)d_in[29];
  const float* h_vb    = (const float*)d_in[30];
  const float* h_ow    = (const float*)d_in[31];
  const float* h_ob    = (const float*)d_in[32];
  const float* h_ln_w  = (const float*)d_in[33];
  const float* h_ln_b  = (const float*)d_in[34];
  const float* h_fc1_w = (const float*)d_in[35];
  const float* h_fc1_b = (const float*)d_in[36];
  const float* h_fc2_w = (const float*)d_in[37];
  const float* h_fc2_b = (const float*)d_in[38];

  const size_t NTOK = (size_t)BATCH * SEQ;                 // 4096
  const size_t ACT  = NTOK * DMODEL;                       // 4.72M elems
  float* hbuf           = (float*)d_ws;                    // residual (f32)
  unsigned short* xa    = (unsigned short*)(hbuf + ACT);   // LN out (bf16)
  unsigned short* qkvb  = xa + ACT;                        // fused qkv (bf16)
  unsigned short* abuf  = qkvb + NTOK * 3456;              // attn out (bf16)
  unsigned short* tb    = qkvb;                            // fc1 out, aliases qkv+abuf
  unsigned short* pxb   = abuf;                            // pixel bf16, aliases abuf
  unsigned short* khb   = qkvb;                            // head K (bf16)
  unsigned short* vhb   = qkvb + ACT;                      // head V (bf16)
  unsigned short* wbufA = abuf + ACT;                      // weight scratch A
  unsigned short* wbufB = wbufA + (size_t)1152 * 4320;     // weight scratch B
  float* smal = (float*)(wbufB + (size_t)1152 * 4320);
  float* hqv  = smal;                                      // 1152
  float* hpb  = hqv + DMODEL;                              // 4x1152
  float* hp2  = hpb + BATCH * DMODEL;
  float* hpn  = hp2 + BATCH * DMODEL;
  float* htb  = hpn + BATCH * DMODEL;                      // 4x4304
  float* bqkv = htb + BATCH * FFDIM;                       // 3456 fused bias
  float* part = hbuf;                                      // splitk partials

  float* out_last   = (float*)d_out;
  float* out_pooled = out_last + ACT;

  const dim3 blk(256), tblk(32, 8);
  const dim3 gD(9, 32), gQKV(27, 32), gF(34, 32);

  // patch embedding (bf16 MFMA, K padded 588->608) + positional add
  cvt_pixel<<<dim3(3, 4096), blk, 0, stream>>>(pixel, pxb);
  transpose_cvt<<<dim3(36, 19), tblk, 0, stream>>>(patch_w, wbufA, 588, 1152, 608);
  gemm_bt<<<gD, blk, 0, stream>>>(pxb, wbufA, patch_b, nullptr, hbuf,
                                  (int)NTOK, 1152, 608, 1152, 1152, 0, 0);
  pos_add_kernel<<<(int)NTOK, 288, 0, stream>>>(pos_emb, sshapes, hbuf);

  for (int l = 0; l < NLAYERS; ++l) {
    const size_t wo = (size_t)l * DMODEL * DMODEL;
    const size_t fo = (size_t)l * DMODEL * FFDIM;
    const size_t bo = (size_t)l * DMODEL;
    const size_t fb = (size_t)l * FFDIM;
    // fused QKV weights -> W^T bf16, fused bias
    transpose_cvt<<<dim3(36, 36), tblk, 0, stream>>>(qw + wo, wbufA, 1152, 1152, 1152);
    transpose_cvt<<<dim3(36, 36), tblk, 0, stream>>>(kw + wo, wbufA + (size_t)1152 * 1152, 1152, 1152, 1152);
    transpose_cvt<<<dim3(36, 36), tblk, 0, stream>>>(vw + wo, wbufA + (size_t)2 * 1152 * 1152, 1152, 1152, 1152);
    concat3<<<5, blk, 0, stream>>>(qb + bo, kb + bo, vb + bo, bqkv, 1152);
    ln_kernel<<<(int)NTOK, blk, 0, stream>>>(hbuf, ln1_w + bo, ln1_b + bo, nullptr, xa);
    gemm_bt<<<gQKV, blk, 0, stream>>>(xa, wbufA, bqkv, nullptr, qkvb,
                                      (int)NTOK, 3456, 1152, 3456, 3456, 0, 1);
    attn_kernel<<<dim3(SEQ / 64, NHEADS, BATCH), blk, 0, stream>>>(qkvb, amask, abuf);
    transpose_cvt<<<dim3(36, 36), tblk, 0, stream>>>(ow + wo, wbufB, 1152, 1152, 1152);
    gemm_bt<<<gD, blk, 0, stream>>>(abuf, wbufB, ob + bo, hbuf, hbuf,
                                    (int)NTOK, 1152, 1152, 1152, 1152, 1, 0);
    ln_kernel<<<(int)NTOK, blk, 0, stream>>>(hbuf, ln2_w + bo, ln2_b + bo, nullptr, xa);
    transpose_cvt<<<dim3(135, 36), tblk, 0, stream>>>(fc1_w + fo, wbufA, 1152, 4304, 1152);
    gemm_bt<<<gF, blk, 0, stream>>>(xa, wbufA, fc1_b + fb, nullptr, tb,
                                    (int)NTOK, 4304, 1152, 4320, 4320, 2, 1);
    transpose_cvt<<<dim3(36, 135), tblk, 0, stream>>>(fc2_w + fo, wbufB, 4304, 1152, 4320);
    gemm_bt<<<gD, blk, 0, stream>>>(tb, wbufB, fc2_b + bo, hbuf, hbuf,
                                    (int)NTOK, 1152, 4320, 1152, 1152, 1, 0);
  }

  // post-LN: f32 -> out_last, bf16 -> xa (head GEMM input)
  ln_kernel<<<(int)NTOK, blk, 0, stream>>>(hbuf, postw, postb, out_last, xa);

  // head K/V projections (MFMA)
  transpose_cvt<<<dim3(36, 36), tblk, 0, stream>>>(h_kw, wbufA, 1152, 1152, 1152);
  gemm_bt<<<gD, blk, 0, stream>>>(xa, wbufA, h_kb, nullptr, khb,
                                  (int)NTOK, 1152, 1152, 1152, 1152, 0, 1);
  transpose_cvt<<<dim3(36, 36), tblk, 0, stream>>>(h_vw, wbufB, 1152, 1152, 1152);
  gemm_bt<<<gD, blk, 0, stream>>>(xa, wbufB, h_vb, nullptr, vhb,
                                  (int)NTOK, 1152, 1152, 1152, 1152, 0, 1);

  // head (split-K GEMVs on f32 weights; `part` aliases dead hbuf)
  const dim3 gv5(5, KSPLIT), gv17(17, KSPLIT);
  gemv_splitk<<<gv5, blk, 0, stream>>>(probe, h_qw, part, 1, DMODEL, DMODEL);
  gemv_reduce<<<dim3(5, 1), blk, 0, stream>>>(part, h_qb, nullptr, hqv, 1, DMODEL, 0);
  head_attn_kernel<<<dim3(NHEADS, BATCH), blk, 0, stream>>>(hqv, khb, vhb, amask, hpb);
  gemv_splitk<<<gv5, blk, 0, stream>>>(hpb, h_ow, part, BATCH, DMODEL, DMODEL);
  gemv_reduce<<<dim3(5, BATCH), blk, 0, stream>>>(part, h_ob, nullptr, hp2, BATCH, DMODEL, 0);
  ln_kernel<<<BATCH, blk, 0, stream>>>(hp2, h_ln_w, h_ln_b, hpn, nullptr);
  gemv_splitk<<<gv17, blk, 0, stream>>>(hpn, h_fc1_w, part, BATCH, FFDIM, DMODEL);
  gemv_reduce<<<dim3(17, BATCH), blk, 0, stream>>>(part, h_fc1_b, nullptr, htb, BATCH, FFDIM, 2);
  gemv_splitk<<<gv5, blk, 0, stream>>>(htb, h_fc2_w, part, BATCH, DMODEL, FFDIM);
  gemv_reduce<<<dim3(5, BATCH), blk, 0, stream>>>(part, h_fc2_b, hp2, out_pooled, BATCH, DMODEL, 1);
}